// Round 10
// baseline (45.000 us; speedup 1.0000x reference)
//
#include <hip/hip_runtime.h>
#include <hip/hip_bf16.h>

#define NB 32
#define NP 4096
#define NC 128
#define ND 128
#define TP 64             // points per tile (16 per wave)
#define TPB 2             // tiles per block (R10)
#define EPSV 1e-16f

typedef __attribute__((ext_vector_type(8))) short short8;
typedef __attribute__((ext_vector_type(4))) short short4v;
typedef __attribute__((ext_vector_type(4))) float f32x4;

__device__ __forceinline__ unsigned short f2bf(float f) {
  __hip_bfloat16 h = __float2bfloat16(f);
  return *reinterpret_cast<unsigned short*>(&h);
}

// LDS byte-offset swizzle for wT: row-major [row][128 bf16], XOR (row&7)<<4.
__device__ __forceinline__ int swz(int row, int kbyte) {
  return (row * 256 + kbyte) ^ ((row & 7) << 4);
}

// Pre-kernel v2 (unchanged from R9): per-record MFMA A-fragment images,
// 32KB/record. Fragment (kk, mi, lane): row d = mi*16 + (lane&15),
// k = kk*32 + (lane>>4)*8 .. +8, bf16x8 (16B). id == (kk*8+mi)*64 + lane.
__global__ void cc_pre(const int* __restrict__ indices,
                       const float* __restrict__ codes,
                       unsigned char* __restrict__ ws) {
  const int b = blockIdx.x >> 3;
  const int chunk = blockIdx.x & 7;
  const int rec = indices[b];
  const float* cb = codes + (size_t)rec * (NC * ND);
  unsigned char* wb = ws + (size_t)b * (NC * ND * 2);
  const int id = chunk * 256 + threadIdx.x;
  const int lane = id & 63;
  const int l16 = lane & 15;
  const int kg = (lane >> 4) & 3;
  const int mi = (id >> 6) & 7;
  const int kk = id >> 9;
  const int d = mi * 16 + l16;
  const int cbase = kk * 32 + kg * 8;
  short8 v;
  #pragma unroll
  for (int j = 0; j < 8; ++j)
    v[j] = (short)f2bf(cb[(size_t)(cbase + j) * ND + d]);
  *(short8*)(wb + ((size_t)id * 16)) = v;
}

// R10: R9's zero-sync structure with 2 tiles per block. phase1(t0),
// phase1(t1), then ONE combined phase 2: each A-fragment loaded once feeds
// both tiles (16 MFMA/fragment-load). Halves block prologues and fragment
// L2 traffic; phase1(t1) covers t0's store drain.
template<bool PRE>
__global__ __launch_bounds__(256, 2) void cc_main(
    const int* __restrict__ indices,
    const float* __restrict__ qp,       // (B,P,3)
    const float* __restrict__ cpos,     // (R,C,3)
    const float* __restrict__ codes,    // (R,C,D)
    const void* __restrict__ dsp,       // dist_scale scalar
    const unsigned char* __restrict__ wsc, // fragment images (v2 layout)
    float* __restrict__ out_qc,         // (B,P,D)
    float* __restrict__ out_sq,         // (B,P,C)
    float* __restrict__ out_wt) {       // (B,P,C)
  __shared__ __align__(16) unsigned char wT[TPB * TP * NC * 2];  // 32KB

  const int tid = threadIdx.x;
  const int lane = tid & 63;
  const int wv = tid >> 6;
  const int g = lane >> 4;            // point-within-quad (phase 1)
  const int l16 = lane & 15;
  const int b = blockIdx.x >> 5;
  const int p0 = (blockIdx.x & 31) * (TP * TPB);
  const int rec = indices[b];
  unsigned char* wTw0 = wT + wv * (16 * 256);           // tile-0 wave section
  unsigned char* wTw1 = wT + 16384 + wv * (16 * 256);   // tile-1 wave section

  const int si = ((const int*)dsp)[0];
  const float sv = (si > 0 && si < 1000) ? (float)si : ((const float*)dsp)[0];

  // ---- per-lane code positions: lane owns codes l16*4..+3 and 64+l16*4..+3
  const float* pb0 = cpos + ((size_t)rec * NC + l16 * 4) * 3;
  const float* pb1 = cpos + ((size_t)rec * NC + 64 + l16 * 4) * 3;
  float px[8], py[8], pz[8];
  #pragma unroll
  for (int j = 0; j < 4; ++j) {
    px[j] = pb0[j * 3 + 0]; py[j] = pb0[j * 3 + 1]; pz[j] = pb0[j * 3 + 2];
    px[j + 4] = pb1[j * 3 + 0]; py[j + 4] = pb1[j * 3 + 1]; pz[j + 4] = pb1[j * 3 + 2];
  }

  const size_t rowbase = (size_t)b * NP + p0;

  // ---- A-fragment source + kk=0 prefetch (hides under both phase-1 passes)
  const unsigned char* fb = wsc + (size_t)b * (NC * ND * 2) + (size_t)lane * 16;
  const float* cb = codes + (size_t)rec * (NC * ND);   // fallback path only
  short8 fA[8], fB[8];
  #pragma unroll
  for (int mi = 0; mi < 8; ++mi) {
    if (PRE) {
      fA[mi] = *(const short8*)(fb + (0 * 8 + mi) * 1024);
    } else {
      const int d = mi * 16 + l16;
      const int cbase0 = g * 8;
      #pragma unroll
      for (int j = 0; j < 8; ++j)
        fA[mi][j] = (short)f2bf(cb[(size_t)(cbase0 + j) * ND + d]);
    }
  }

  // ---- phase 1 for both tiles (wave-local; lane owns 8 codes, 4+4 split)
  const bool s2 = (sv == 2.0f);
  #pragma unroll
  for (int t = 0; t < TPB; ++t) {
    unsigned char* wTw = t ? wTw1 : wTw0;
    #pragma unroll
    for (int it = 0; it < 4; ++it) {
      const int p = t * TP + wv * 16 + it * 4 + g;
      const float* q = qp + (rowbase + p) * 3;
      const float qx = q[0], qy = q[1], qz = q[2];

      float dd[8], wu[8];
      #pragma unroll
      for (int j = 0; j < 8; ++j) {
        const float dx = qx - px[j], dy = qy - py[j], dz = qz - pz[j];
        dd[j] = fmaf(dx, dx, fmaf(dy, dy, dz * dz)) + EPSV;
      }
      if (s2) {
        #pragma unroll
        for (int j = 0; j < 8; ++j) wu[j] = __builtin_amdgcn_rcpf(dd[j]);
      } else {
        #pragma unroll
        for (int j = 0; j < 8; ++j) wu[j] = __powf(dd[j], -0.5f * sv);
      }
      float s = ((wu[0] + wu[1]) + (wu[2] + wu[3])) + ((wu[4] + wu[5]) + (wu[6] + wu[7]));
      s += __shfl_xor(s, 1); s += __shfl_xor(s, 2);
      s += __shfl_xor(s, 4); s += __shfl_xor(s, 8);   // within 16-lane group
      const float inv = __builtin_amdgcn_rcpf(s);

      f32x4 dlo, dhi, wlo, whi;
      #pragma unroll
      for (int j = 0; j < 4; ++j) {
        dlo[j] = dd[j]; dhi[j] = dd[j + 4];
        wlo[j] = wu[j] * inv; whi[j] = wu[j + 4] * inv;
      }
      const size_t rb = (rowbase + p) * (size_t)NC;
      *(f32x4*)(out_sq + rb + l16 * 4) = dlo;
      *(f32x4*)(out_sq + rb + 64 + l16 * 4) = dhi;
      *(f32x4*)(out_wt + rb + l16 * 4) = wlo;
      *(f32x4*)(out_wt + rb + 64 + l16 * 4) = whi;

      short4v wbl, wbh;
      #pragma unroll
      for (int j = 0; j < 4; ++j) {
        wbl[j] = (short)f2bf(wlo[j]);
        wbh[j] = (short)f2bf(whi[j]);
      }
      const int r = it * 4 + g;
      *(short4v*)(wTw + swz(r, l16 * 8)) = wbl;        // codes l16*4..+3
      *(short4v*)(wTw + swz(r, 128 + l16 * 8)) = wbh;  // codes 64+l16*4..+3
    }
  }

  // ---- combined phase 2: NO barrier (per-wave LDS ops are in-order).
  // Each A-fragment used for both tiles; pipelined one k-step ahead.
  const int kg = lane >> 4;
  f32x4 acc[2][8];
  #pragma unroll
  for (int t = 0; t < 2; ++t)
    #pragma unroll
    for (int mi = 0; mi < 8; ++mi)
      acc[t][mi] = (f32x4){0.f, 0.f, 0.f, 0.f};

  #define LOADF(dst, kknext)                                                   \
    _Pragma("unroll")                                                          \
    for (int mi = 0; mi < 8; ++mi) {                                           \
      if (PRE) {                                                               \
        dst[mi] = *(const short8*)(fb + ((kknext) * 8 + mi) * 1024);           \
      } else {                                                                 \
        const int d = mi * 16 + l16;                                           \
        const int cb0 = (kknext) * 32 + g * 8;                                 \
        _Pragma("unroll")                                                      \
        for (int j = 0; j < 8; ++j)                                            \
          dst[mi][j] = (short)f2bf(cb[(size_t)(cb0 + j) * ND + d]);            \
      }                                                                        \
    }

  #define COMPUTE2(src, kk)                                                    \
    {                                                                          \
      const int kb = ((kk) * 32 + kg * 8) * 2;                                 \
      const short8 b0 = *(const short8*)(wTw0 + swz(l16, kb));                 \
      const short8 b1 = *(const short8*)(wTw1 + swz(l16, kb));                 \
      _Pragma("unroll")                                                        \
      for (int mi = 0; mi < 8; ++mi) {                                         \
        acc[0][mi] = __builtin_amdgcn_mfma_f32_16x16x32_bf16(src[mi], b0,      \
                                                            acc[0][mi], 0,0,0);\
        acc[1][mi] = __builtin_amdgcn_mfma_f32_16x16x32_bf16(src[mi], b1,      \
                                                            acc[1][mi], 0,0,0);\
      }                                                                        \
    }

  LOADF(fB, 1)
  COMPUTE2(fA, 0)
  LOADF(fA, 2)
  COMPUTE2(fB, 1)
  LOADF(fB, 3)
  COMPUTE2(fA, 2)
  COMPUTE2(fB, 3)

  #undef LOADF
  #undef COMPUTE2

  // D layout: col(=p-offset) = lane&15, row(=d-offset) = (lane>>4)*4 + reg
  #pragma unroll
  for (int t = 0; t < 2; ++t) {
    float* o = out_qc + (rowbase + t * TP + wv * 16 + l16) * (size_t)ND + kg * 4;
    #pragma unroll
    for (int mi = 0; mi < 8; ++mi)
      *(f32x4*)(o + mi * 16) = acc[t][mi];
  }
}

extern "C" void kernel_launch(void* const* d_in, const int* in_sizes, int n_in,
                              void* d_out, int out_size, void* d_ws, size_t ws_size,
                              hipStream_t stream) {
  const int* indices = (const int*)d_in[0];
  const float* qp = (const float*)d_in[1];
  const float* cpos = (const float*)d_in[2];
  const float* codes = (const float*)d_in[3];
  const void* dsp = d_in[4];

  float* out = (float*)d_out;
  float* qc = out;                                   // (B,P,D)
  float* sq = qc + (size_t)NB * NP * ND;             // (B,P,C)
  float* wt = sq + (size_t)NB * NP * NC;             // (B,P,C)

  const size_t ws_need = (size_t)NB * NC * ND * 2;   // 1 MiB
  dim3 grid(NB * (NP / (TP * TPB)));                 // 1024 blocks
  if (ws_size >= ws_need) {
    cc_pre<<<dim3(NB * 8), dim3(256), 0, stream>>>(indices, codes, (unsigned char*)d_ws);
    cc_main<true><<<grid, 256, 0, stream>>>(indices, qp, cpos, codes, dsp,
                                            (const unsigned char*)d_ws, qc, sq, wt);
  } else {
    cc_main<false><<<grid, 256, 0, stream>>>(indices, qp, cpos, codes, dsp,
                                             nullptr, qc, sq, wt);
  }
}